// Round 2
// baseline (431.336 us; speedup 1.0000x reference)
//
#include <hip/hip_runtime.h>
#include <hip/hip_bf16.h>

typedef float        f32x4  __attribute__((ext_vector_type(4)));
typedef __bf16       bf16x8 __attribute__((ext_vector_type(8)));
typedef unsigned int u32x4  __attribute__((ext_vector_type(4)));

// ws layout
#define S1_OFF   0u
#define S1_BYTES (64u * 8192u * 32u)            // 16,777,216 B (bitpacked s1: [t][b][256 bits])
#define WB_OFF   S1_BYTES
#define WB_BYTES (4u * 8u * 4u * 3u * 1024u)    // 393,216 B (W_h 3-way bf16 splits, fragment-linear)
#define PART_OFF (WB_OFF + WB_BYTES)
#define NPART    256

static __device__ __forceinline__ float clamp01(float v) {
    return fminf(fmaxf(v, 0.0f), 1.0f);
}
static __device__ __forceinline__ unsigned short f2bf(float f) {  // RNE float->bf16
    unsigned int u = __builtin_bit_cast(unsigned int, f);
    u += 0x7FFFu + ((u >> 16) & 1u);
    return (unsigned short)(u >> 16);
}
static __device__ __forceinline__ float bf2f(unsigned short b) {
    unsigned int u = ((unsigned int)b) << 16;
    return __builtin_bit_cast(float, u);
}

// ---------------------------------------------------------------------------
// k0: split W_h into 3 bf16 parts (hi+mid+lo ~= fp32), fragment-linear layout
// for mfma_f32_16x16x32_bf16 B-operand:
//   lane = (h&15) | (((d>>3)&3)<<4) ; elem j = d&7
//   frag id (per 64-col block nb): ((ks*4 + nfq)*3 + sp), 1024 B each
// ---------------------------------------------------------------------------
__global__ void k0_prepW(const float* __restrict__ W_h,
                         unsigned short* __restrict__ WB) {
    int id = blockIdx.x * 256 + threadIdx.x;   // 65536 = h*256 + d
    int h = id >> 8, d = id & 255;
    float w = W_h[id];
    unsigned short s0 = f2bf(w);
    float r1 = w - bf2f(s0);
    unsigned short s1 = f2bf(r1);
    float r2 = r1 - bf2f(s1);
    unsigned short s2 = f2bf(r2);
    int nb = h >> 6, nfq = (h >> 4) & 3, colL = h & 15;
    int ks = d >> 5, lsel = (d >> 3) & 3, j = d & 7;
    int lane = colL | (lsel << 4);
    size_t base = (size_t)nb * 49152u + (size_t)((ks * 4 + nfq) * 3) * 512u
                + (size_t)lane * 8u + (size_t)j;       // u16 units
    WB[base]        = s0;
    WB[base + 512]  = s1;
    WB[base + 1024] = s2;
}

// ---------------------------------------------------------------------------
// k1: cur_in = x_t @ W_in^T + b_in (fp32), 64-step layer-1 recurrence,
// s1 bitpacked via __ballot.  8 batches/block, 1024 blocks (4 blocks/CU).
// Thread: lane owns h = {lane, lane+64, lane+128, lane+192}; grp = tid>>6
// owns batches {grp*2, grp*2+1}.
// ---------------------------------------------------------------------------
__global__ __launch_bounds__(256) void k1_layer1(
    const float* __restrict__ x, const float* __restrict__ W_in,
    const float* __restrict__ b_in, const float* __restrict__ beta_in,
    const float* __restrict__ thr_in, unsigned long long* __restrict__ S1) {
    __shared__ float Xs[8][256];
    int tid = threadIdx.x;
    int b0 = blockIdx.x * 8;
    #pragma unroll
    for (int i = 0; i < 8; ++i) {
        int idx = i * 256 + tid;
        int bb = idx >> 8, d = idx & 255;
        Xs[bb][d] = x[((size_t)(b0 + bb) * 256 + d) * 64];  // x[0,b,d,0]
    }
    __syncthreads();

    int lane = tid & 63, grp = tid >> 6;
    int   h[4]; float bi[4], b1[4], th[4];
    #pragma unroll
    for (int i = 0; i < 4; ++i) {
        h[i]  = i * 64 + lane;
        bi[i] = b_in[h[i]];
        b1[i] = clamp01(beta_in[h[i]]);
        th[i] = thr_in[h[i]];
    }
    float cur[4][2];
    #pragma unroll
    for (int i = 0; i < 4; ++i)
        #pragma unroll
        for (int bb = 0; bb < 2; ++bb) cur[i][bb] = bi[i];

    #pragma unroll 4
    for (int d4 = 0; d4 < 64; ++d4) {
        f32x4 w[4];
        #pragma unroll
        for (int i = 0; i < 4; ++i)
            w[i] = *(const f32x4*)(W_in + (size_t)h[i] * 256 + d4 * 4);
        #pragma unroll
        for (int bb = 0; bb < 2; ++bb) {
            f32x4 xv = *(const f32x4*)(&Xs[grp * 2 + bb][d4 * 4]);
            #pragma unroll
            for (int i = 0; i < 4; ++i)
                cur[i][bb] += w[i][0]*xv[0] + w[i][1]*xv[1] + w[i][2]*xv[2] + w[i][3]*xv[3];
        }
    }

    float m1[4][2];
    #pragma unroll
    for (int i = 0; i < 4; ++i)
        #pragma unroll
        for (int bb = 0; bb < 2; ++bb) m1[i][bb] = 0.0f;

    #pragma unroll 1
    for (int t = 0; t < 64; ++t) {
        #pragma unroll
        for (int i = 0; i < 4; ++i) {
            #pragma unroll
            for (int bb = 0; bb < 2; ++bb) {
                float mm = m1[i][bb];
                float rst = (mm > th[i]) ? th[i] : 0.0f;   // r1*thr (r1 uses old m1)
                mm = b1[i] * mm + cur[i][bb] - rst;
                m1[i][bb] = mm;
                unsigned long long bal = __ballot(mm > th[i]);  // s1 bits, d = i*64+lane
                if (lane == 0)
                    S1[((size_t)t * 8192 + (size_t)(b0 + grp * 2 + bb)) * 4 + i] = bal;
            }
        }
    }
}

// ---------------------------------------------------------------------------
// k2: fused 64-step loop: cur_h = s1 @ W_h^T (triple-bf16 MFMA) + layer-2
// recurrence + layer-3 linear accumulation.  Grid (64,4): x = 128-batch tile,
// y = 64-col block.  512 thr = 8 waves (2/SIMD); wave tile M=32 x N=32.
// No barriers inside the t-loop; W splits in LDS; m2 in registers.
// ---------------------------------------------------------------------------
__global__ __launch_bounds__(512) void k2_main(
    const unsigned int* __restrict__ S1,
    const u32x4* __restrict__ WB,
    const float* __restrict__ b_h, const float* __restrict__ beta_h,
    const float* __restrict__ thr_h, const float* __restrict__ W_o,
    const float* __restrict__ beta_o, float* __restrict__ partials) {
    __shared__ u32x4 Blds[6144];   // 96 KB
    __shared__ float wred[8];
    int tid = threadIdx.x, lane = tid & 63, wid = tid >> 6;

    const u32x4* src = WB + (size_t)blockIdx.y * 6144;
    #pragma unroll
    for (int k = 0; k < 12; ++k) Blds[k * 512 + tid] = src[k * 512 + tid];
    __syncthreads();

    int mq = wid & 3, nh = wid >> 2;
    int colL = lane & 15, ksel = lane >> 4;
    int rowbase = blockIdx.x * 128 + mq * 32 + colL;

    float thr[2], b2[2], wo[2], bh[2];
    #pragma unroll
    for (int nf = 0; nf < 2; ++nf) {
        int hcol = blockIdx.y * 64 + nh * 32 + nf * 16 + colL;
        thr[nf] = thr_h[hcol];
        b2[nf]  = clamp01(beta_h[hcol]);
        wo[nf]  = W_o[hcol];
        bh[nf]  = b_h[hcol];
    }
    float b3 = clamp01(beta_o[0]);

    const f32x4 zf = {0.0f, 0.0f, 0.0f, 0.0f};
    f32x4 m2[2][2];
    #pragma unroll
    for (int m = 0; m < 2; ++m)
        #pragma unroll
        for (int nf = 0; nf < 2; ++nf) m2[m][nf] = zf;
    float acc3 = 0.0f;

    #pragma unroll 1
    for (int t = 0; t < 64; ++t) {
        const unsigned int* Srow = S1 + (size_t)t * 65536;  // 8192 rows * 8 u32

        // load full bit-rows (32 B each) for this wave's 32 batch rows
        u32x4 q[2][2];
        #pragma unroll
        for (int m = 0; m < 2; ++m) {
            const u32x4* rp = (const u32x4*)(Srow + (size_t)(rowbase + m * 16) * 8);
            q[m][0] = rp[0];
            q[m][1] = rp[1];
        }

        f32x4 acc[2][2];
        #pragma unroll
        for (int m = 0; m < 2; ++m)
            #pragma unroll
            for (int nf = 0; nf < 2; ++nf)
                acc[m][nf] = (f32x4){bh[nf], bh[nf], bh[nf], bh[nf]};

        #pragma unroll
        for (int ks = 0; ks < 8; ++ks) {
            bf16x8 a[2];
            #pragma unroll
            for (int m = 0; m < 2; ++m) {
                unsigned int w  = q[m][ks >> 2][ks & 3];
                unsigned int by = (w >> (ksel * 8)) & 0xFFu;
                u32x4 uw;
                uw[0] = ((by & 1u)  ? 0x3F80u : 0u) | ((by & 2u)   ? 0x3F800000u : 0u);
                uw[1] = ((by & 4u)  ? 0x3F80u : 0u) | ((by & 8u)   ? 0x3F800000u : 0u);
                uw[2] = ((by & 16u) ? 0x3F80u : 0u) | ((by & 32u)  ? 0x3F800000u : 0u);
                uw[3] = ((by & 64u) ? 0x3F80u : 0u) | ((by & 128u) ? 0x3F800000u : 0u);
                a[m] = __builtin_bit_cast(bf16x8, uw);
            }
            #pragma unroll
            for (int nf = 0; nf < 2; ++nf) {
                int nfq = nh * 2 + nf;
                #pragma unroll
                for (int sp = 0; sp < 3; ++sp) {
                    bf16x8 bfr = __builtin_bit_cast(bf16x8,
                        Blds[((ks * 4 + nfq) * 3 + sp) * 64 + lane]);
                    #pragma unroll
                    for (int m = 0; m < 2; ++m)
                        acc[m][nf] = __builtin_amdgcn_mfma_f32_16x16x32_bf16(
                            a[m], bfr, acc[m][nf], 0, 0, 0);
                }
            }
        }
        // layer-2 recurrence + layer-3 linear accumulation
        float sum = 0.0f;
        #pragma unroll
        for (int m = 0; m < 2; ++m)
            #pragma unroll
            for (int nf = 0; nf < 2; ++nf)
                #pragma unroll
                for (int r = 0; r < 4; ++r) {
                    float cv  = acc[m][nf][r];              // cur_h (bias folded in)
                    float mm  = m2[m][nf][r];
                    float rst = (mm > thr[nf]) ? thr[nf] : 0.0f;  // r2 uses old m2
                    mm = b2[nf] * mm + cv - rst;
                    m2[m][nf][r] = mm;
                    if (mm > thr[nf]) sum += wo[nf];        // s2 * w_o
                }
        acc3 = b3 * acc3 + sum;   // m3 linear: final = sum_t b3^(63-t) * cur_o[t]
    }

    #pragma unroll
    for (int off = 32; off; off >>= 1) acc3 += __shfl_xor(acc3, off);
    if (lane == 0) wred[wid] = acc3;
    __syncthreads();
    if (tid == 0) {
        float s = 0.0f;
        #pragma unroll
        for (int wq = 0; wq < 8; ++wq) s += wred[wq];
        partials[blockIdx.y * 64 + blockIdx.x] = s;
    }
}

// ---------------------------------------------------------------------------
// k3: deterministic final reduction + bias/geometric term
// ---------------------------------------------------------------------------
__global__ void k3_final(const float* __restrict__ partials,
                         const float* __restrict__ b_o,
                         const float* __restrict__ beta_o,
                         float* __restrict__ out) {
    __shared__ float wred[4];
    int tid = threadIdx.x, lane = tid & 63, wid = tid >> 6;
    float v = partials[tid];
    #pragma unroll
    for (int off = 32; off; off >>= 1) v += __shfl_xor(v, off);
    if (lane == 0) wred[wid] = v;
    __syncthreads();
    if (tid == 0) {
        float total = (wred[0] + wred[1]) + (wred[2] + wred[3]);
        float b3 = clamp01(beta_o[0]);
        float geo = 0.0f, p = 1.0f;
        #pragma unroll 1
        for (int i = 0; i < 64; ++i) { geo += p; p *= b3; }
        out[0] = total / 8192.0f + b_o[0] * geo;
    }
}

extern "C" void kernel_launch(void* const* d_in, const int* in_sizes, int n_in,
                              void* d_out, int out_size, void* d_ws, size_t ws_size,
                              hipStream_t stream) {
    const float* x       = (const float*)d_in[0];
    const float* W_in    = (const float*)d_in[1];
    const float* b_in    = (const float*)d_in[2];
    const float* beta_in = (const float*)d_in[3];
    const float* thr_in  = (const float*)d_in[4];
    const float* W_h     = (const float*)d_in[5];
    const float* b_h     = (const float*)d_in[6];
    const float* beta_h  = (const float*)d_in[7];
    const float* thr_h   = (const float*)d_in[8];
    const float* W_o     = (const float*)d_in[9];
    const float* b_o     = (const float*)d_in[10];
    const float* beta_o  = (const float*)d_in[11];
    (void)in_sizes; (void)n_in; (void)out_size; (void)ws_size;

    char* ws = (char*)d_ws;
    unsigned long long* S1 = (unsigned long long*)(ws + S1_OFF);
    unsigned short*     WB = (unsigned short*)(ws + WB_OFF);
    float*        partials = (float*)(ws + PART_OFF);

    k0_prepW <<<256, 256, 0, stream>>>(W_h, WB);
    k1_layer1<<<1024, 256, 0, stream>>>(x, W_in, b_in, beta_in, thr_in, S1);
    k2_main  <<<dim3(64, 4), 512, 0, stream>>>((const unsigned int*)S1, (const u32x4*)WB,
                                               b_h, beta_h, thr_h, W_o, beta_o, partials);
    k3_final <<<1, 256, 0, stream>>>(partials, b_o, beta_o, (float*)d_out);
}

// Round 3
// 376.608 us; speedup vs baseline: 1.1453x; 1.1453x over previous
//
#include <hip/hip_runtime.h>
#include <hip/hip_bf16.h>

typedef float        f32x4  __attribute__((ext_vector_type(4)));
typedef int          i32x4  __attribute__((ext_vector_type(4)));
typedef unsigned int u32x2  __attribute__((ext_vector_type(2)));

// ws layout
#define S1_OFF   0u
#define S1_BYTES (64u * 8192u * 32u)            // 16,777,216 B (bitpacked s1: [t][b][256 bits], bit p = d)
#define WB_OFF   S1_BYTES
#define WB_BYTES (16u * 8u * 3u * 512u)         // 196,608 B (W_h 3-digit i8 splits, fragment-linear)
#define PART_OFF (WB_OFF + WB_BYTES)

static __device__ __forceinline__ float clamp01(float v) {
    return fminf(fmaxf(v, 0.0f), 1.0f);
}

// ---------------------------------------------------------------------------
// k0: W_h -> 3 signed-i8 base-256 digits: w = a0*2^-7 + a1*2^-15 + a2*2^-23,
// |err| <= 2^-24.  Fragment-linear layout for v_mfma_i32_16x16x32_i8 B-op:
//   B[k][col=h]: lane = (h&15) + 16*(k_local>>3), byte j = k_local&7
//   global k = ks*32 + k_local ; spike bit at physical pos d maps to
//   k with field swap: d = lsel*64 + ks*8 + j  ->  k = ks*32 + lsel*8 + j.
// Frag f = ((nfq*8 + ks)*3 + sp), 512 B each (64 lanes x 8 B).
// Thread: id = h*32 + d8 handles d = d8*8 .. +7 (one 8-byte lane-slot per sp).
// ---------------------------------------------------------------------------
__global__ void k0_prepW(const float* __restrict__ W_h,
                         unsigned long long* __restrict__ WB64) {
    int id = blockIdx.x * 256 + threadIdx.x;   // 8192 threads
    int h = id >> 5, d8 = id & 31;
    int ks = d8 & 7, lsel = d8 >> 3;
    int nfq = h >> 4, colL = h & 15;
    int lane = colL + 16 * lsel;

    unsigned long long v0 = 0, v1 = 0, v2 = 0;
    #pragma unroll
    for (int j = 0; j < 8; ++j) {
        float w  = W_h[h * 256 + d8 * 8 + j];
        float a0 = rintf(w * 128.0f);
        float e1 = fmaf(a0, -0x1p-7f, w);
        float a1 = rintf(e1 * 0x1p15f);
        if (a1 == 128.0f) { a1 = -128.0f; a0 += 1.0f; }
        float e2 = fmaf(a1, -0x1p-15f, e1);
        float a2 = rintf(e2 * 0x1p23f);
        if (a2 == 128.0f) {
            a2 = -128.0f; a1 += 1.0f;
            if (a1 == 128.0f) { a1 = -128.0f; a0 += 1.0f; }
        }
        v0 |= (unsigned long long)(unsigned char)(signed char)(int)a0 << (8 * j);
        v1 |= (unsigned long long)(unsigned char)(signed char)(int)a1 << (8 * j);
        v2 |= (unsigned long long)(unsigned char)(signed char)(int)a2 << (8 * j);
    }
    size_t f = (size_t)(nfq * 8 + ks) * 3;
    WB64[(f + 0) * 64 + lane] = v0;
    WB64[(f + 1) * 64 + lane] = v1;
    WB64[(f + 2) * 64 + lane] = v2;
}

// ---------------------------------------------------------------------------
// k1: cur_in = x_t @ W_in^T + b_in (fp32), 64-step layer-1 recurrence,
// s1 bitpacked via __ballot (bit p = d, identity).  8 batches/block,
// 1024 blocks.  lane owns h = {lane, +64, +128, +192}; grp = tid>>6 owns
// batches {grp*2, grp*2+1}.
// ---------------------------------------------------------------------------
__global__ __launch_bounds__(256) void k1_layer1(
    const float* __restrict__ x, const float* __restrict__ W_in,
    const float* __restrict__ b_in, const float* __restrict__ beta_in,
    const float* __restrict__ thr_in, unsigned long long* __restrict__ S1) {
    __shared__ float Xs[8][256];
    int tid = threadIdx.x;
    int b0 = blockIdx.x * 8;
    #pragma unroll
    for (int i = 0; i < 8; ++i) {
        int idx = i * 256 + tid;
        int bb = idx >> 8, d = idx & 255;
        Xs[bb][d] = x[((size_t)(b0 + bb) * 256 + d) * 64];  // x[0,b,d,0]
    }
    __syncthreads();

    int lane = tid & 63, grp = tid >> 6;
    int   h[4]; float bi[4], b1[4], th[4];
    #pragma unroll
    for (int i = 0; i < 4; ++i) {
        h[i]  = i * 64 + lane;
        bi[i] = b_in[h[i]];
        b1[i] = clamp01(beta_in[h[i]]);
        th[i] = thr_in[h[i]];
    }
    float cur[4][2];
    #pragma unroll
    for (int i = 0; i < 4; ++i)
        #pragma unroll
        for (int bb = 0; bb < 2; ++bb) cur[i][bb] = bi[i];

    #pragma unroll 4
    for (int d4 = 0; d4 < 64; ++d4) {
        f32x4 w[4];
        #pragma unroll
        for (int i = 0; i < 4; ++i)
            w[i] = *(const f32x4*)(W_in + (size_t)h[i] * 256 + d4 * 4);
        #pragma unroll
        for (int bb = 0; bb < 2; ++bb) {
            f32x4 xv = *(const f32x4*)(&Xs[grp * 2 + bb][d4 * 4]);
            #pragma unroll
            for (int i = 0; i < 4; ++i)
                cur[i][bb] += w[i][0]*xv[0] + w[i][1]*xv[1] + w[i][2]*xv[2] + w[i][3]*xv[3];
        }
    }

    float m1[4][2];
    #pragma unroll
    for (int i = 0; i < 4; ++i)
        #pragma unroll
        for (int bb = 0; bb < 2; ++bb) m1[i][bb] = 0.0f;

    #pragma unroll 1
    for (int t = 0; t < 64; ++t) {
        #pragma unroll
        for (int i = 0; i < 4; ++i) {
            #pragma unroll
            for (int bb = 0; bb < 2; ++bb) {
                float mm = m1[i][bb];
                float rst = (mm > th[i]) ? th[i] : 0.0f;   // r1 uses old m1
                mm = b1[i] * mm + cur[i][bb] - rst;
                m1[i][bb] = mm;
                unsigned long long bal = __ballot(mm > th[i]);  // s1 bits, d = i*64+lane
                if (lane == 0)
                    S1[((size_t)t * 8192 + (size_t)(b0 + grp * 2 + bb)) * 4 + i] = bal;
            }
        }
    }
}

// ---------------------------------------------------------------------------
// k2: fused 64-step loop, i8 MFMA, zero LDS in t-loop.
// 256 blocks x 512 thr (8 waves = 2/SIMD).  Block owns 32 batch rows x all
// 256 h cols; wave wid owns cols [wid*32, wid*32+32).  All 48 B-fragments
// (2 nfq x 3 sp x 8 ks) live in VGPRs.  Per t: one dwordx2/lane of spike
// bits per 16-row group, ~7-op bit->i8 unpack, 96 MFMAs, fp32 combine +
// layer-2 recurrence + layer-3 linear accumulation.
// ---------------------------------------------------------------------------
__global__ __launch_bounds__(512, 2) void k2_main(
    const unsigned int* __restrict__ S1,
    const unsigned long long* __restrict__ WB64,
    const float* __restrict__ b_h, const float* __restrict__ beta_h,
    const float* __restrict__ thr_h, const float* __restrict__ W_o,
    const float* __restrict__ beta_o, float* __restrict__ partials) {
    __shared__ float wred[8];
    int tid = threadIdx.x, lane = tid & 63, wid = tid >> 6;
    int colL = lane & 15, lsel = lane >> 4;
    int row0 = blockIdx.x * 32;

    // persistent B fragments in registers
    long Bf[2][3][8];
    #pragma unroll
    for (int nf2 = 0; nf2 < 2; ++nf2) {
        int nfq = wid * 2 + nf2;
        #pragma unroll
        for (int ks = 0; ks < 8; ++ks)
            #pragma unroll
            for (int sp = 0; sp < 3; ++sp)
                Bf[nf2][sp][ks] =
                    (long)WB64[(size_t)((nfq * 8 + ks) * 3 + sp) * 64 + lane];
    }

    float thr[2], b2[2], wo[2], bh[2];
    #pragma unroll
    for (int nf2 = 0; nf2 < 2; ++nf2) {
        int hcol = wid * 32 + nf2 * 16 + colL;
        thr[nf2] = thr_h[hcol];
        b2[nf2]  = clamp01(beta_h[hcol]);
        wo[nf2]  = W_o[hcol];
        bh[nf2]  = b_h[hcol];
    }
    float b3 = clamp01(beta_o[0]);

    float m2[2][2][4], rstv[2][2][4];
    #pragma unroll
    for (int m = 0; m < 2; ++m)
        #pragma unroll
        for (int nf2 = 0; nf2 < 2; ++nf2)
            #pragma unroll
            for (int r = 0; r < 4; ++r) { m2[m][nf2][r] = 0.0f; rstv[m][nf2][r] = 0.0f; }
    float acc3 = 0.0f;

    size_t qoff[2];
    #pragma unroll
    for (int m = 0; m < 2; ++m)
        qoff[m] = (size_t)(row0 + m * 16 + colL) * 8 + (size_t)lsel * 2;  // u32 units

    auto STEP = [&](const u32x2 (&q)[2]) {
        i32x4 acc[3][2][2];
        #pragma unroll
        for (int sp = 0; sp < 3; ++sp)
            #pragma unroll
            for (int m = 0; m < 2; ++m)
                #pragma unroll
                for (int nf2 = 0; nf2 < 2; ++nf2)
                    acc[sp][m][nf2] = (i32x4){0, 0, 0, 0};

        #pragma unroll
        for (int ks = 0; ks < 8; ++ks) {
            long a[2];
            #pragma unroll
            for (int m = 0; m < 2; ++m) {
                unsigned int by = (q[m][ks >> 2] >> ((ks & 3) * 8)) & 0xFFu;
                unsigned int lo = (by & 0xFu) * 0x204081u & 0x01010101u;
                unsigned int hi = (by >> 4)   * 0x204081u & 0x01010101u;
                u32x2 av = {lo, hi};
                a[m] = __builtin_bit_cast(long, av);
            }
            #pragma unroll
            for (int m = 0; m < 2; ++m)
                #pragma unroll
                for (int nf2 = 0; nf2 < 2; ++nf2)
                    #pragma unroll
                    for (int sp = 0; sp < 3; ++sp)
                        acc[sp][m][nf2] = __builtin_amdgcn_mfma_i32_16x16x32_i8(
                            a[m], Bf[nf2][sp][ks], acc[sp][m][nf2], 0, 0, 0);
        }

        float sum = 0.0f;
        #pragma unroll
        for (int m = 0; m < 2; ++m)
            #pragma unroll
            for (int nf2 = 0; nf2 < 2; ++nf2)
                #pragma unroll
                for (int r = 0; r < 4; ++r) {
                    float cur = fmaf((float)acc[0][m][nf2][r], 0x1p-7f,
                                fmaf((float)acc[1][m][nf2][r], 0x1p-15f,
                                fmaf((float)acc[2][m][nf2][r], 0x1p-23f, bh[nf2])));
                    float mm = fmaf(b2[nf2], m2[m][nf2][r], cur) - rstv[m][nf2][r];
                    m2[m][nf2][r] = mm;
                    bool s = mm > thr[nf2];
                    rstv[m][nf2][r] = s ? thr[nf2] : 0.0f;
                    sum += s ? wo[nf2] : 0.0f;
                }
        acc3 = fmaf(b3, acc3, sum);
    };

    u32x2 qA[2], qB[2];
    #pragma unroll
    for (int m = 0; m < 2; ++m) qA[m] = *(const u32x2*)(S1 + qoff[m]);

    #pragma unroll 1
    for (int t = 0; t < 64; t += 2) {
        #pragma unroll
        for (int m = 0; m < 2; ++m)
            qB[m] = *(const u32x2*)(S1 + (size_t)(t + 1) * 65536 + qoff[m]);
        STEP(qA);
        if (t + 2 < 64) {
            #pragma unroll
            for (int m = 0; m < 2; ++m)
                qA[m] = *(const u32x2*)(S1 + (size_t)(t + 2) * 65536 + qoff[m]);
        }
        STEP(qB);
    }

    #pragma unroll
    for (int off = 32; off; off >>= 1) acc3 += __shfl_xor(acc3, off);
    if (lane == 0) wred[wid] = acc3;
    __syncthreads();
    if (tid == 0) {
        float s = 0.0f;
        #pragma unroll
        for (int wq = 0; wq < 8; ++wq) s += wred[wq];
        partials[blockIdx.x] = s;
    }
}

// ---------------------------------------------------------------------------
// k3: deterministic final reduction + bias/geometric term
// ---------------------------------------------------------------------------
__global__ void k3_final(const float* __restrict__ partials,
                         const float* __restrict__ b_o,
                         const float* __restrict__ beta_o,
                         float* __restrict__ out) {
    __shared__ float wred[4];
    int tid = threadIdx.x, lane = tid & 63, wid = tid >> 6;
    float v = partials[tid];
    #pragma unroll
    for (int off = 32; off; off >>= 1) v += __shfl_xor(v, off);
    if (lane == 0) wred[wid] = v;
    __syncthreads();
    if (tid == 0) {
        float total = (wred[0] + wred[1]) + (wred[2] + wred[3]);
        float b3 = clamp01(beta_o[0]);
        float geo = 0.0f, p = 1.0f;
        #pragma unroll 1
        for (int i = 0; i < 64; ++i) { geo += p; p *= b3; }
        out[0] = total / 8192.0f + b_o[0] * geo;
    }
}

extern "C" void kernel_launch(void* const* d_in, const int* in_sizes, int n_in,
                              void* d_out, int out_size, void* d_ws, size_t ws_size,
                              hipStream_t stream) {
    const float* x       = (const float*)d_in[0];
    const float* W_in    = (const float*)d_in[1];
    const float* b_in    = (const float*)d_in[2];
    const float* beta_in = (const float*)d_in[3];
    const float* thr_in  = (const float*)d_in[4];
    const float* W_h     = (const float*)d_in[5];
    const float* b_h     = (const float*)d_in[6];
    const float* beta_h  = (const float*)d_in[7];
    const float* thr_h   = (const float*)d_in[8];
    const float* W_o     = (const float*)d_in[9];
    const float* b_o     = (const float*)d_in[10];
    const float* beta_o  = (const float*)d_in[11];
    (void)in_sizes; (void)n_in; (void)out_size; (void)ws_size;

    char* ws = (char*)d_ws;
    unsigned long long* S1 = (unsigned long long*)(ws + S1_OFF);
    unsigned long long* WB = (unsigned long long*)(ws + WB_OFF);
    float*        partials = (float*)(ws + PART_OFF);

    k0_prepW <<<32,   256, 0, stream>>>(W_h, WB);
    k1_layer1<<<1024, 256, 0, stream>>>(x, W_in, b_in, beta_in, thr_in, S1);
    k2_main  <<<256,  512, 0, stream>>>((const unsigned int*)S1, WB,
                                        b_h, beta_h, thr_h, W_o, beta_o, partials);
    k3_final <<<1, 256, 0, stream>>>(partials, b_o, beta_o, (float*)d_out);
}

// Round 4
// 344.416 us; speedup vs baseline: 1.2524x; 1.0935x over previous
//
#include <hip/hip_runtime.h>
#include <hip/hip_bf16.h>

typedef float              f32x4 __attribute__((ext_vector_type(4)));
typedef int                i32x4 __attribute__((ext_vector_type(4)));
typedef unsigned int       u32x2 __attribute__((ext_vector_type(2)));
typedef unsigned long long u64x2 __attribute__((ext_vector_type(2)));

// ws layout
#define S1_OFF   0u
#define S1_BYTES (64u * 8192u * 32u)   // 16,777,216 B (bitpacked s1: [t][b][256 bits], bit p = d)
#define PART_OFF S1_BYTES

static __device__ __forceinline__ float clamp01(float v) {
    return fminf(fmaxf(v, 0.0f), 1.0f);
}

// ---------------------------------------------------------------------------
// k1: cur_in = x_t @ W_in^T + b_in (fp32), 64-step layer-1 recurrence,
// s1 bitpacked via __ballot.  8 batches/block, 1024 blocks.
// lane owns h = {lane, +64, +128, +192}; grp = tid>>6 owns batches
// {grp*2, grp*2+1}.  Per t the wave's 8 ballot words (one 64-B region)
// are scattered to lanes 0-3 and stored as two u64 per lane (1 txn vs 8).
// ---------------------------------------------------------------------------
__global__ __launch_bounds__(256) void k1_layer1(
    const float* __restrict__ x, const float* __restrict__ W_in,
    const float* __restrict__ b_in, const float* __restrict__ beta_in,
    const float* __restrict__ thr_in, unsigned long long* __restrict__ S1) {
    __shared__ float Xs[8][256];
    int tid = threadIdx.x;
    int b0 = blockIdx.x * 8;
    #pragma unroll
    for (int i = 0; i < 8; ++i) {
        int idx = i * 256 + tid;
        int bb = idx >> 8, d = idx & 255;
        Xs[bb][d] = x[((size_t)(b0 + bb) * 256 + d) * 64];  // x[0,b,d,0]
    }
    __syncthreads();

    int lane = tid & 63, grp = tid >> 6;
    int   h[4]; float bi[4], b1[4], th[4];
    #pragma unroll
    for (int i = 0; i < 4; ++i) {
        h[i]  = i * 64 + lane;
        bi[i] = b_in[h[i]];
        b1[i] = clamp01(beta_in[h[i]]);
        th[i] = thr_in[h[i]];
    }
    float cur[4][2];
    #pragma unroll
    for (int i = 0; i < 4; ++i)
        #pragma unroll
        for (int bb = 0; bb < 2; ++bb) cur[i][bb] = bi[i];

    #pragma unroll 4
    for (int d4 = 0; d4 < 64; ++d4) {
        f32x4 w[4];
        #pragma unroll
        for (int i = 0; i < 4; ++i)
            w[i] = *(const f32x4*)(W_in + (size_t)h[i] * 256 + d4 * 4);
        #pragma unroll
        for (int bb = 0; bb < 2; ++bb) {
            f32x4 xv = *(const f32x4*)(&Xs[grp * 2 + bb][d4 * 4]);
            #pragma unroll
            for (int i = 0; i < 4; ++i)
                cur[i][bb] += w[i][0]*xv[0] + w[i][1]*xv[1] + w[i][2]*xv[2] + w[i][3]*xv[3];
        }
    }

    float m1[4][2];
    #pragma unroll
    for (int i = 0; i < 4; ++i)
        #pragma unroll
        for (int bb = 0; bb < 2; ++bb) m1[i][bb] = 0.0f;

    int li = lane & 3;
    #pragma unroll 1
    for (int t = 0; t < 64; ++t) {
        unsigned long long arr[8];
        #pragma unroll
        for (int i = 0; i < 4; ++i) {
            #pragma unroll
            for (int bb = 0; bb < 2; ++bb) {
                float mm = m1[i][bb];
                float rst = (mm > th[i]) ? th[i] : 0.0f;   // r1 uses old m1
                mm = b1[i] * mm + cur[i][bb] - rst;
                m1[i][bb] = mm;
                arr[bb * 4 + i] = __ballot(mm > th[i]);    // s1 bits, d = i*64+lane
            }
        }
        // lane li stores arr[2*li], arr[2*li+1] (u64 linear idx = bb*4+i)
        unsigned long long e0 = (li & 2) ? ((li & 1) ? arr[6] : arr[4])
                                         : ((li & 1) ? arr[2] : arr[0]);
        unsigned long long e1 = (li & 2) ? ((li & 1) ? arr[7] : arr[5])
                                         : ((li & 1) ? arr[3] : arr[1]);
        if (lane < 4) {
            unsigned long long* p =
                S1 + ((size_t)t * 8192 + (size_t)(b0 + grp * 2)) * 4 + (size_t)li * 2;
            *(u64x2*)p = (u64x2){e0, e1};
        }
    }
}

// ---------------------------------------------------------------------------
// k2: prologue splits W_h into 3 signed-i8 base-256 digits directly into
// VGPRs (w = a0*2^-7 + a1*2^-15 + a2*2^-23, |err| <= 2^-24; exact int
// extraction), then fused 64-step loop with i8 MFMA, zero LDS in t-loop.
// 256 blocks x 512 thr (8 waves = 2/SIMD).  Block owns 32 batch rows x all
// 256 h cols; wave wid owns cols [wid*32, +32).  Fragment mapping:
//   B[k][col=h]: lane = colL + 16*lsel, byte j; h = nfq*16 + colL,
//   d = lsel*64 + ks*8 + j  (k = ks*32 + lsel*8 + j).
// ---------------------------------------------------------------------------
__global__ __launch_bounds__(512, 2) void k2_main(
    const unsigned int* __restrict__ S1,
    const float* __restrict__ W_h,
    const float* __restrict__ b_h, const float* __restrict__ beta_h,
    const float* __restrict__ thr_h, const float* __restrict__ W_o,
    const float* __restrict__ beta_o, float* __restrict__ partials) {
    __shared__ float wred[8];
    int tid = threadIdx.x, lane = tid & 63, wid = tid >> 6;
    int colL = lane & 15, lsel = lane >> 4;
    int row0 = blockIdx.x * 32;

    // ---- prologue: build persistent B digit-fragments in registers ----
    long Bf[2][3][8];
    #pragma unroll
    for (int nf2 = 0; nf2 < 2; ++nf2) {
        int hrow = (wid * 2 + nf2) * 16 + colL;
        #pragma unroll
        for (int ks = 0; ks < 8; ++ks) {
            const float* wp = W_h + (size_t)hrow * 256 + lsel * 64 + ks * 8;
            unsigned int lo[3] = {0, 0, 0}, hi[3] = {0, 0, 0};
            #pragma unroll
            for (int j = 0; j < 8; ++j) {
                float w = wp[j];
                int v  = (int)rintf(w * 0x1p23f);
                int a2 = ((v + 128) & 255) - 128;  v = (v - a2) >> 8;
                int a1 = ((v + 128) & 255) - 128;  int a0 = (v - a1) >> 8;
                unsigned int sh = (j & 3) * 8;
                unsigned int* dst = (j < 4) ? lo : hi;
                dst[0] |= (unsigned int)(a0 & 255) << sh;
                dst[1] |= (unsigned int)(a1 & 255) << sh;
                dst[2] |= (unsigned int)(a2 & 255) << sh;
            }
            #pragma unroll
            for (int sp = 0; sp < 3; ++sp) {
                u32x2 pk = {lo[sp], hi[sp]};
                Bf[nf2][sp][ks] = __builtin_bit_cast(long, pk);
            }
        }
    }

    float thr[2], b2[2], wo[2], bh[2];
    #pragma unroll
    for (int nf2 = 0; nf2 < 2; ++nf2) {
        int hcol = wid * 32 + nf2 * 16 + colL;
        thr[nf2] = thr_h[hcol];
        b2[nf2]  = clamp01(beta_h[hcol]);
        wo[nf2]  = W_o[hcol];
        bh[nf2]  = b_h[hcol];
    }
    float b3 = clamp01(beta_o[0]);

    float m2[2][2][4], rstv[2][2][4];
    #pragma unroll
    for (int m = 0; m < 2; ++m)
        #pragma unroll
        for (int nf2 = 0; nf2 < 2; ++nf2)
            #pragma unroll
            for (int r = 0; r < 4; ++r) { m2[m][nf2][r] = 0.0f; rstv[m][nf2][r] = 0.0f; }
    float acc3 = 0.0f;

    size_t qoff[2];
    #pragma unroll
    for (int m = 0; m < 2; ++m)
        qoff[m] = (size_t)(row0 + m * 16 + colL) * 8 + (size_t)lsel * 2;  // u32 units

    auto STEP = [&](const u32x2 (&q)[2]) {
        i32x4 acc[3][2][2];
        #pragma unroll
        for (int sp = 0; sp < 3; ++sp)
            #pragma unroll
            for (int m = 0; m < 2; ++m)
                #pragma unroll
                for (int nf2 = 0; nf2 < 2; ++nf2)
                    acc[sp][m][nf2] = (i32x4){0, 0, 0, 0};

        #pragma unroll
        for (int ks = 0; ks < 8; ++ks) {
            long a[2];
            #pragma unroll
            for (int m = 0; m < 2; ++m) {
                unsigned int by = (q[m][ks >> 2] >> ((ks & 3) * 8)) & 0xFFu;
                unsigned int lo = (by & 0xFu) * 0x204081u & 0x01010101u;
                unsigned int hi = (by >> 4)   * 0x204081u & 0x01010101u;
                u32x2 av = {lo, hi};
                a[m] = __builtin_bit_cast(long, av);
            }
            #pragma unroll
            for (int m = 0; m < 2; ++m)
                #pragma unroll
                for (int nf2 = 0; nf2 < 2; ++nf2)
                    #pragma unroll
                    for (int sp = 0; sp < 3; ++sp)
                        acc[sp][m][nf2] = __builtin_amdgcn_mfma_i32_16x16x32_i8(
                            a[m], Bf[nf2][sp][ks], acc[sp][m][nf2], 0, 0, 0);
        }

        float sum = 0.0f;
        #pragma unroll
        for (int m = 0; m < 2; ++m)
            #pragma unroll
            for (int nf2 = 0; nf2 < 2; ++nf2)
                #pragma unroll
                for (int r = 0; r < 4; ++r) {
                    int   s01 = (acc[0][m][nf2][r] << 8) + acc[1][m][nf2][r];  // exact, <2^23
                    float cur = fmaf((float)s01, 0x1p-15f,
                                fmaf((float)acc[2][m][nf2][r], 0x1p-23f, bh[nf2]));
                    float mm = fmaf(b2[nf2], m2[m][nf2][r], cur) - rstv[m][nf2][r];
                    m2[m][nf2][r] = mm;
                    bool s = mm > thr[nf2];
                    rstv[m][nf2][r] = s ? thr[nf2] : 0.0f;
                    sum += s ? wo[nf2] : 0.0f;
                }
        acc3 = fmaf(b3, acc3, sum);
    };

    u32x2 qA[2], qB[2];
    #pragma unroll
    for (int m = 0; m < 2; ++m) qA[m] = *(const u32x2*)(S1 + qoff[m]);

    #pragma unroll 1
    for (int t = 0; t < 64; t += 2) {
        #pragma unroll
        for (int m = 0; m < 2; ++m)
            qB[m] = *(const u32x2*)(S1 + (size_t)(t + 1) * 65536 + qoff[m]);
        STEP(qA);
        if (t + 2 < 64) {
            #pragma unroll
            for (int m = 0; m < 2; ++m)
                qA[m] = *(const u32x2*)(S1 + (size_t)(t + 2) * 65536 + qoff[m]);
        }
        STEP(qB);
    }

    #pragma unroll
    for (int off = 32; off; off >>= 1) acc3 += __shfl_xor(acc3, off);
    if (lane == 0) wred[wid] = acc3;
    __syncthreads();
    if (tid == 0) {
        float s = 0.0f;
        #pragma unroll
        for (int wq = 0; wq < 8; ++wq) s += wred[wq];
        partials[blockIdx.x] = s;
    }
}

// ---------------------------------------------------------------------------
// k3: deterministic final reduction + bias/geometric term
// ---------------------------------------------------------------------------
__global__ void k3_final(const float* __restrict__ partials,
                         const float* __restrict__ b_o,
                         const float* __restrict__ beta_o,
                         float* __restrict__ out) {
    __shared__ float wred[4];
    int tid = threadIdx.x, lane = tid & 63, wid = tid >> 6;
    float v = partials[tid];
    #pragma unroll
    for (int off = 32; off; off >>= 1) v += __shfl_xor(v, off);
    if (lane == 0) wred[wid] = v;
    __syncthreads();
    if (tid == 0) {
        float total = (wred[0] + wred[1]) + (wred[2] + wred[3]);
        float b3 = clamp01(beta_o[0]);
        float geo = 0.0f, p = 1.0f;
        #pragma unroll 1
        for (int i = 0; i < 64; ++i) { geo += p; p *= b3; }
        out[0] = total / 8192.0f + b_o[0] * geo;
    }
}

extern "C" void kernel_launch(void* const* d_in, const int* in_sizes, int n_in,
                              void* d_out, int out_size, void* d_ws, size_t ws_size,
                              hipStream_t stream) {
    const float* x       = (const float*)d_in[0];
    const float* W_in    = (const float*)d_in[1];
    const float* b_in    = (const float*)d_in[2];
    const float* beta_in = (const float*)d_in[3];
    const float* thr_in  = (const float*)d_in[4];
    const float* W_h     = (const float*)d_in[5];
    const float* b_h     = (const float*)d_in[6];
    const float* beta_h  = (const float*)d_in[7];
    const float* thr_h   = (const float*)d_in[8];
    const float* W_o     = (const float*)d_in[9];
    const float* b_o     = (const float*)d_in[10];
    const float* beta_o  = (const float*)d_in[11];
    (void)in_sizes; (void)n_in; (void)out_size; (void)ws_size;

    char* ws = (char*)d_ws;
    unsigned long long* S1 = (unsigned long long*)(ws + S1_OFF);
    float*        partials = (float*)(ws + PART_OFF);

    k1_layer1<<<1024, 256, 0, stream>>>(x, W_in, b_in, beta_in, thr_in, S1);
    k2_main  <<<256,  512, 0, stream>>>((const unsigned int*)S1, W_h,
                                        b_h, beta_h, thr_h, W_o, beta_o, partials);
    k3_final <<<1, 256, 0, stream>>>(partials, b_o, beta_o, (float*)d_out);
}